// Round 2
// baseline (242.730 us; speedup 1.0000x reference)
//
#include <hip/hip_runtime.h>
#include <math.h>

// GraphLearner: per-edge cosine similarity + sigmoid + straight-through hard threshold.
//   out[e] = let v = sigmoid(cos(f1,f2)/T) in (v <= 0.5 ? 0 : v)
//
// R2 design: ONE thread per edge (R1's 16-lanes/edge was VALU-bound at 94%
// VALUBusy — shuffle reduction cost ~4x the FMA work). Each thread streams
// both 64-float rows with 32 dwordx4 loads (256 B contiguous per row), no
// cross-lane ops. Index loads and output writes stay coalesced.
//
// Accumulation order replicates numpy pairwise_sum for n=64: eight stride-8
// accumulators r0..r7 (here two float4s: even/odd float4-chunks), combined
// ((r0+r1)+(r2+r3)) + ((r4+r5)+(r6+r7)) — keeps fp divergence from the np
// reference minimal (matters near the v==0.5 hard-threshold discontinuity).

#define D 64
#define BLOCK 256
#define COS_EPS 1e-6f

#define FMA4(A, X, Y) \
    A.x += X.x * Y.x; A.y += X.y * Y.y; A.z += X.z * Y.z; A.w += X.w * Y.w;

#define PAIRWISE8(E, O) \
    (((E.x + E.y) + (E.z + E.w)) + ((O.x + O.y) + (O.z + O.w)))

__global__ __launch_bounds__(BLOCK) void GraphLearner_68513318306086_kernel(
    const float* __restrict__ node_embs,
    const int*   __restrict__ edge_index,
    const int*   __restrict__ temp_ptr,
    float*       __restrict__ out,
    int n_edges)
{
    int e = blockIdx.x * BLOCK + threadIdx.x;
    if (e >= n_edges) return;

    // temperature: 1-element array; reference passes Python int 1.
    // Accept either int32 or float32 encoding.
    int tbits = *temp_ptr;
    float T;
    if (tbits >= 1 && tbits < (1 << 23)) {
        T = (float)tbits;
    } else {
        union { int i; float f; } u; u.i = tbits; T = u.f;
    }

    int i0 = edge_index[e];             // edge_index row 0
    int i1 = edge_index[n_edges + e];   // edge_index row 1

    const float4* __restrict__ r0 = (const float4*)(node_embs + (size_t)i0 * D);
    const float4* __restrict__ r1 = (const float4*)(node_embs + (size_t)i1 * D);

    float4 z = make_float4(0.f, 0.f, 0.f, 0.f);
    float4 dE = z, dO = z;   // dot accumulators (even/odd float4 chunks)
    float4 aE = z, aO = z;   // |f1|^2 accumulators
    float4 bE = z, bO = z;   // |f2|^2 accumulators

    #pragma unroll
    for (int k = 0; k < D / 4; k += 2) {
        float4 x0 = r0[k];     float4 y0 = r1[k];
        float4 x1 = r0[k + 1]; float4 y1 = r1[k + 1];
        FMA4(dE, x0, y0)
        FMA4(aE, x0, x0)
        FMA4(bE, y0, y0)
        FMA4(dO, x1, y1)
        FMA4(aO, x1, x1)
        FMA4(bO, y1, y1)
    }

    float dot = PAIRWISE8(dE, dO);
    float n1s = PAIRWISE8(aE, aO);
    float n2s = PAIRWISE8(bE, bO);

    float d1   = fmaxf(sqrtf(n1s), COS_EPS);
    float d2   = fmaxf(sqrtf(n2s), COS_EPS);
    float cosv = dot / (d1 * d2);
    float v    = 1.0f / (1.0f + expf(-(cosv / T)));
    out[e] = (v <= 0.5f) ? 0.0f : v;    // straight-through hard threshold
}

extern "C" void kernel_launch(void* const* d_in, const int* in_sizes, int n_in,
                              void* d_out, int out_size, void* d_ws, size_t ws_size,
                              hipStream_t stream) {
    const float* node_embs  = (const float*)d_in[0];
    const int*   edge_index = (const int*)d_in[1];
    const int*   temp_ptr   = (const int*)d_in[2];
    float*       out        = (float*)d_out;

    int n_edges = in_sizes[1] / 2;      // edge_index is [2, E]

    int grid = (n_edges + BLOCK - 1) / BLOCK;
    GraphLearner_68513318306086_kernel<<<grid, BLOCK, 0, stream>>>(
        node_embs, edge_index, temp_ptr, out, n_edges);
}

// Round 3
// 201.287 us; speedup vs baseline: 1.2059x; 1.2059x over previous
//
#include <hip/hip_runtime.h>
#include <math.h>

// GraphLearner: per-edge cosine similarity + sigmoid + straight-through threshold.
//   out[e] = let v = sigmoid(cos(f1,f2)/T) in (v <= 0.5 ? 0 : v)
//
// R3 design:
//  - Kernel 1: per-node clamped norm d[n] = max(sqrt(sumsq(row_n)), eps), computed
//    one-thread-per-node with numpy pairwise_sum accumulator order (bit-exact vs
//    the np reference, verified bit-exact by R2's absmax=0.0).
//  - Kernel 2: 8 lanes per edge. Each lane loads 2 float4s per row, so 8 lanes
//    cover each 128 B cache line in ONE load instruction -> minimal TA line
//    requests (R2's 1-thread/edge did 8x the requests and was latency-bound;
//    R1's 16-lanes/edge was VALU-bound at 94% from shuffle overhead).
//    Dot reduced with a 3-level xor tree; norms come from the precomputed table.

#define D 64
#define BLOCK 256
#define COS_EPS 1e-6f
#define N_NODES_EXPECTED 100000

#define FMA4(A, X, Y) \
    A.x += X.x * Y.x; A.y += X.y * Y.y; A.z += X.z * Y.z; A.w += X.w * Y.w;

// numpy pairwise_sum combination for 8 accumulators r0..r7 packed as two float4s
#define PAIRWISE8(E, O) \
    (((E.x + E.y) + (E.z + E.w)) + ((O.x + O.y) + (O.z + O.w)))

__device__ __forceinline__ float read_temperature(const int* temp_ptr) {
    int tbits = *temp_ptr;
    if (tbits >= 1 && tbits < (1 << 23)) return (float)tbits;  // int32 temperature
    union { int i; float f; } u; u.i = tbits; return u.f;      // float32 bits
}

// Kernel 1: per-node clamped norm, numpy accumulation order (bit-exact).
__global__ __launch_bounds__(BLOCK) void node_norm_kernel(
    const float* __restrict__ node_embs,
    float*       __restrict__ dnorm,
    int n_nodes)
{
    int n = blockIdx.x * BLOCK + threadIdx.x;
    if (n >= n_nodes) return;

    const float4* __restrict__ r = (const float4*)(node_embs + (size_t)n * D);
    float4 z = make_float4(0.f, 0.f, 0.f, 0.f);
    float4 aE = z, aO = z;   // r[0..3] / r[4..7] numpy accumulators
    #pragma unroll
    for (int k = 0; k < D / 4; k += 2) {
        float4 x0 = r[k];
        float4 x1 = r[k + 1];
        FMA4(aE, x0, x0)
        FMA4(aO, x1, x1)
    }
    float s = PAIRWISE8(aE, aO);
    dnorm[n] = fmaxf(sqrtf(s), COS_EPS);
}

// Kernel 2: 8 lanes per edge.
__global__ __launch_bounds__(BLOCK) void GraphLearner_68513318306086_kernel(
    const float* __restrict__ node_embs,
    const int*   __restrict__ edge_index,
    const float* __restrict__ dnorm,
    const int*   __restrict__ temp_ptr,
    float*       __restrict__ out,
    int n_edges)
{
    int t    = blockIdx.x * BLOCK + threadIdx.x;
    int e    = t >> 3;              // edge index (8 lanes per edge)
    int lane = threadIdx.x & 7;
    if (e >= n_edges) return;

    int i0 = edge_index[e];             // edge_index row 0
    int i1 = edge_index[n_edges + e];   // edge_index row 1

    const float4* __restrict__ r0 = (const float4*)(node_embs + (size_t)i0 * D);
    const float4* __restrict__ r1 = (const float4*)(node_embs + (size_t)i1 * D);

    // lane covers chunks {lane, lane+8}: 8 lanes span each 128 B line per instr
    float4 x0 = r0[lane];
    float4 x1 = r0[lane + 8];
    float4 y0 = r1[lane];
    float4 y1 = r1[lane + 8];

    float pE = (x0.x * y0.x + x0.y * y0.y) + (x0.z * y0.z + x0.w * y0.w);
    float pO = (x1.x * y1.x + x1.y * y1.y) + (x1.z * y1.z + x1.w * y1.w);
    float p  = pE + pO;

    // 3-level xor tree across the 8-lane group
    p += __shfl_xor(p, 1, 8);
    p += __shfl_xor(p, 2, 8);
    p += __shfl_xor(p, 4, 8);

    if (lane == 0) {
        float T    = read_temperature(temp_ptr);
        float d1   = dnorm[i0];
        float d2   = dnorm[i1];
        float cosv = p / (d1 * d2);
        float v    = 1.0f / (1.0f + expf(-(cosv / T)));
        out[e] = (v <= 0.5f) ? 0.0f : v;    // straight-through hard threshold
    }
}

// Fallback (ws too small): 8 lanes/edge with inline norm tree reduction.
__global__ __launch_bounds__(BLOCK) void edge_kernel_fused(
    const float* __restrict__ node_embs,
    const int*   __restrict__ edge_index,
    const int*   __restrict__ temp_ptr,
    float*       __restrict__ out,
    int n_edges)
{
    int t    = blockIdx.x * BLOCK + threadIdx.x;
    int e    = t >> 3;
    int lane = threadIdx.x & 7;
    if (e >= n_edges) return;

    int i0 = edge_index[e];
    int i1 = edge_index[n_edges + e];

    const float4* __restrict__ r0 = (const float4*)(node_embs + (size_t)i0 * D);
    const float4* __restrict__ r1 = (const float4*)(node_embs + (size_t)i1 * D);

    float4 x0 = r0[lane];
    float4 x1 = r0[lane + 8];
    float4 y0 = r1[lane];
    float4 y1 = r1[lane + 8];

    float p  = ((x0.x * y0.x + x0.y * y0.y) + (x0.z * y0.z + x0.w * y0.w))
             + ((x1.x * y1.x + x1.y * y1.y) + (x1.z * y1.z + x1.w * y1.w));
    float a  = ((x0.x * x0.x + x0.y * x0.y) + (x0.z * x0.z + x0.w * x0.w))
             + ((x1.x * x1.x + x1.y * x1.y) + (x1.z * x1.z + x1.w * x1.w));
    float b  = ((y0.x * y0.x + y0.y * y0.y) + (y0.z * y0.z + y0.w * y0.w))
             + ((y1.x * y1.x + y1.y * y1.y) + (y1.z * y1.z + y1.w * y1.w));

    #pragma unroll
    for (int m = 1; m < 8; m <<= 1) {
        p += __shfl_xor(p, m, 8);
        a += __shfl_xor(a, m, 8);
        b += __shfl_xor(b, m, 8);
    }

    if (lane == 0) {
        float T    = read_temperature(temp_ptr);
        float d1   = fmaxf(sqrtf(a), COS_EPS);
        float d2   = fmaxf(sqrtf(b), COS_EPS);
        float cosv = p / (d1 * d2);
        float v    = 1.0f / (1.0f + expf(-(cosv / T)));
        out[e] = (v <= 0.5f) ? 0.0f : v;
    }
}

extern "C" void kernel_launch(void* const* d_in, const int* in_sizes, int n_in,
                              void* d_out, int out_size, void* d_ws, size_t ws_size,
                              hipStream_t stream) {
    const float* node_embs  = (const float*)d_in[0];
    const int*   edge_index = (const int*)d_in[1];
    const int*   temp_ptr   = (const int*)d_in[2];
    float*       out        = (float*)d_out;

    int n_nodes = in_sizes[0] / D;      // node_embs is [N, 64]
    int n_edges = in_sizes[1] / 2;      // edge_index is [2, E]

    int grid_e = (n_edges * 8 + BLOCK - 1) / BLOCK;

    if (ws_size >= (size_t)n_nodes * sizeof(float)) {
        float* dnorm = (float*)d_ws;
        int grid_n = (n_nodes + BLOCK - 1) / BLOCK;
        node_norm_kernel<<<grid_n, BLOCK, 0, stream>>>(node_embs, dnorm, n_nodes);
        GraphLearner_68513318306086_kernel<<<grid_e, BLOCK, 0, stream>>>(
            node_embs, edge_index, dnorm, temp_ptr, out, n_edges);
    } else {
        edge_kernel_fused<<<grid_e, BLOCK, 0, stream>>>(
            node_embs, edge_index, temp_ptr, out, n_edges);
    }
}